// Round 12
// baseline (110.506 us; speedup 1.0000x reference)
//
#include <hip/hip_runtime.h>
#include <cstdint>
#include <cstddef>

typedef __bf16 bf16;
typedef bf16 bf16x8 __attribute__((ext_vector_type(8)));
typedef float f32x4 __attribute__((ext_vector_type(4)));

typedef __attribute__((address_space(1))) void as1_void;
typedef __attribute__((address_space(3))) void as3_void;

__device__ __forceinline__ void gload16(const void* g, void* l) {
  __builtin_amdgcn_global_load_lds((const as1_void*)g, (as3_void*)l, 16, 0, 0);
}

// ---------------- attention (tiny, exact f32) ----------------
__global__ __launch_bounds__(256) void attn_kernel(
    const float* __restrict__ ref, const float* __restrict__ w1,
    const float* __restrict__ w2, const float* __restrict__ b2,
    const float* __restrict__ bias, float* __restrict__ attn,
    float* __restrict__ aggb) {
  const int b = blockIdx.x, t = threadIdx.x;
  __shared__ float pooled[256];
  __shared__ float hsh[65];
  __shared__ float ash[4];
  {
    const float* r = ref + ((size_t)b * 256 + t) * 64;
    float s = 0.f;
    #pragma unroll
    for (int l = 0; l < 64; l += 4) {
      float4 v = *(const float4*)(r + l);
      s += v.x + v.y + v.z + v.w;
    }
    pooled[t] = s * (1.0f / 64.0f);
  }
  __syncthreads();
  if (t < 65) {
    const float* w = w1 + t * 256;
    float s = 0.f;
    for (int p = 0; p < 256; ++p) s += pooled[p] * w[p];
    hsh[t] = fmaxf(s, 0.f);
  }
  __syncthreads();
  if (t == 0) {
    float lg[4];
    for (int k = 0; k < 4; ++k) {
      float s = b2[k];
      for (int j = 0; j < 65; ++j) s += hsh[j] * w2[k * 65 + j];
      lg[k] = s * (1.0f / 34.0f);
    }
    float m = fmaxf(fmaxf(lg[0], lg[1]), fmaxf(lg[2], lg[3]));
    float e[4], se = 0.f;
    for (int k = 0; k < 4; ++k) { e[k] = expf(lg[k] - m); se += e[k]; }
    float inv = 1.0f / se;
    for (int k = 0; k < 4; ++k) { float a = e[k] * inv; ash[k] = a; attn[b * 4 + k] = a; }
  }
  __syncthreads();
  {
    float s = 0.f;
    for (int k = 0; k < 4; ++k) s += ash[k] * bias[k * 256 + t];
    aggb[b * 256 + t] = s;
  }
}

// ---------------- weight aggregation -> bf16, [b][o][s*256+i] ----------------
__global__ __launch_bounds__(256) void aggw_kernel(
    const float* __restrict__ weight, const float* __restrict__ attn,
    bf16* __restrict__ Wagg) {
  const int o = blockIdx.x, b = blockIdx.y, i = threadIdx.x;
  const float a0 = attn[b * 4 + 0], a1 = attn[b * 4 + 1];
  const float a2 = attn[b * 4 + 2], a3 = attn[b * 4 + 3];
  const size_t ks = (size_t)256 * 256 * 3;
  const float* w = weight + ((size_t)o * 256 + i) * 3;
  bf16* dst = Wagg + ((size_t)(b * 256 + o)) * 768 + i;
  #pragma unroll
  for (int s = 0; s < 3; ++s) {
    float v = a0 * w[s] + a1 * w[ks + s] + a2 * w[2 * ks + s] + a3 * w[3 * ks + s];
    dst[s * 256] = (bf16)v;
  }
}

// ---------------- conv-as-GEMM, 256x256 block, 128x128 wave tile ----------------
// 256 threads / 4 waves (2x2), wave tile 128x128, acc[8][8] = 256 regs at
// 1 wave/SIMD (512-reg budget: acc 256 + frags 64 + xv 64 fits, no cap).
// Pipe balance per CU per K-step: LDS 128 b128-reads (~1536 cyc shared pipe)
// < MFMA 128/wave x 16 cyc = 2048 cyc/SIMD -> MFMA-dominant (first time).
// NO intra-step barriers: compiler pipelines kk1 reads under kk0's MFMA
// block. One __syncthreads per step (W dbuf swap); X tile swap per i-block.
__global__ __launch_bounds__(256) void conv_kernel(
    const float* __restrict__ x, const bf16* __restrict__ Wagg,
    const float* __restrict__ aggb, float* __restrict__ out) {
  __shared__ bf16 Wl[2][256 * 64];   // 64 KB dbuf, 256 o-rows x 64 k
  __shared__ bf16 Xl[258 * 64];      // 33 KB, rows l0-1 .. l0+256
  const int tid = threadIdx.x;
  const int lane = tid & 63, wid = tid >> 6;
  // XCD swizzle: 512 blocks, 8 XCDs -> 64 consecutive swz per XCD = 4 batches.
  const int bid = blockIdx.x;
  const int swz = (bid & 7) * 64 + (bid >> 3);
  const int b  = swz >> 4;
  const int lt = swz & 15;
  const int l0 = lt * 256;
  const int wm = wid >> 1, wn = wid & 1;
  const float* xb = x + (size_t)b * 256 * 4096;
  const bf16* Wb = Wagg + (size_t)b * 256 * 768;
  f32x4 acc[8][8] = {};

  // W staging: step slice k = (t%3)*256 + (t/3)*64, rows 0..255 (all o).
  auto stage_w = [&](int t, int buf) {
    const int ss = t % 3, ibb = t / 3;
    const int koff = ss * 256 + ibb * 64;
    char* base = (char*)&Wl[buf][0];
    #pragma unroll
    for (int inst = 0; inst < 8; ++inst) {
      int c = inst * 256 + tid;
      int row = c >> 3, subg = (c & 7) ^ (row & 7);
      gload16(Wb + (size_t)row * 768 + koff + subg * 8,
              base + (inst * 256 + wid * 64) * 16);
    }
  };

  // ---- X staging (R10's proven math, 256-thread version) ----
  const int lq = tid & 63;          // l-quad: rows 1+4lq .. 4+4lq
  const int sg = tid >> 6;          // i-octet (part A: sg, part B: sg+4)
  const float* xqA = xb + ((size_t)sg * 8) * 4096 + l0 + lq * 4;
  const float* xqB = xb + ((size_t)(sg + 4) * 8) * 4096 + l0 + lq * 4;
  const int ei = tid >> 1;          // tid<128: edge i 0..63
  const int erow = (tid & 1) ? 257 : 0;
  const int el = (tid & 1) ? (l0 + 256) : (l0 - 1);
  const bool edge_ok = (el >= 0) && (el < 4096);
  float4 xvA[8], xvB[8];
  float ev = 0.f;

  auto load_x = [&](int ib) {
    const float* pA = xqA + (size_t)ib * 64 * 4096;
    const float* pB = xqB + (size_t)ib * 64 * 4096;
    #pragma unroll
    for (int r = 0; r < 8; ++r) {
      xvA[r] = *(const float4*)(pA + (size_t)r * 4096);
      xvB[r] = *(const float4*)(pB + (size_t)r * 4096);
    }
    if (tid < 128)
      ev = edge_ok ? xb[(size_t)(ib * 64 + ei) * 4096 + el] : 0.f;
  };
  auto write_x = [&]() {
    char* base = (char*)&Xl[0];
    #pragma unroll
    for (int q = 0; q < 4; ++q) {
      const int row = lq * 4 + 1 + q;
      bf16x8 pkA, pkB;
      #pragma unroll
      for (int r = 0; r < 8; ++r) {
        pkA[r] = (bf16)(((const float*)&xvA[r])[q]);
        pkB[r] = (bf16)(((const float*)&xvB[r])[q]);
      }
      *(bf16x8*)(base + row * 128 + ((sg ^ (row & 7)) << 4)) = pkA;
      *(bf16x8*)(base + row * 128 + (((sg + 4) ^ (row & 7)) << 4)) = pkB;
    }
    if (tid < 128)
      *(bf16*)(base + erow * 128 + (((ei >> 3) ^ (erow & 7)) << 4) + (ei & 7) * 2)
          = (bf16)ev;
  };

  // ---- prologue ----
  load_x(0);
  stage_w(0, 0);
  stage_w(1, 1);
  write_x();
  __syncthreads();   // drains W0,W1 gloads (vmcnt) + X ds_writes (lgkm)

  for (int J = 0; J < 4; ++J) {
    #pragma unroll
    for (int s = 0; s < 3; ++s) {
      const int t = J * 3 + s;
      const char* wbuf = (const char*)&Wl[(J + s) & 1][0];   // (J*3+s)&1
      const char* xbuf = (const char*)&Xl[0];
      if (t < 11) stage_w(t + 1, (t + 1) & 1);
      if (s == 2 && J < 3) load_x(J + 1);    // 17 loads, land by write_x
      #pragma unroll
      for (int kk = 0; kk < 2; ++kk) {
        const int sub = (lane >> 4) + kk * 4;
        bf16x8 af[8], bfr[8];
        #pragma unroll
        for (int j = 0; j < 8; ++j) {
          int row = wm * 128 + j * 16 + (lane & 15);
          af[j] = *(const bf16x8*)(wbuf + row * 128 + ((sub ^ (row & 7)) << 4));
        }
        #pragma unroll
        for (int n = 0; n < 8; ++n) {
          int row = wn * 128 + n * 16 + (lane & 15) + s;   // +s = conv shift
          bfr[n] = *(const bf16x8*)(xbuf + row * 128 + ((sub ^ (row & 7)) << 4));
        }
        #pragma unroll
        for (int j = 0; j < 8; ++j)
          #pragma unroll
          for (int n = 0; n < 8; ++n)
            acc[j][n] = __builtin_amdgcn_mfma_f32_16x16x32_bf16(af[j], bfr[n], acc[j][n], 0, 0, 0);
      }
      if (t < 11) __syncthreads();   // one barrier per step (W swap safety)
    }
    if (J < 3) {
      write_x();        // all waves past step barrier => Xl reads done
      __syncthreads();  // new X tile visible
    }
  }

  const int b256 = b * 256;
  #pragma unroll
  for (int j = 0; j < 8; ++j) {
    const int ob = wm * 128 + j * 16 + ((lane >> 4) << 2);
    float bb[4];
    #pragma unroll
    for (int r = 0; r < 4; ++r) bb[r] = aggb[b256 + ob + r];
    #pragma unroll
    for (int n = 0; n < 8; ++n) {
      const int l = l0 + wn * 128 + n * 16 + (lane & 15);
      f32x4 v = acc[j][n];
      #pragma unroll
      for (int r = 0; r < 4; ++r)
        out[((size_t)(b256 + ob + r)) * 4096 + l] = v[r] + bb[r];
    }
  }
}

extern "C" void kernel_launch(void* const* d_in, const int* in_sizes, int n_in,
                              void* d_out, int out_size, void* d_ws, size_t ws_size,
                              hipStream_t stream) {
  const float* ref    = (const float*)d_in[0];
  const float* x      = (const float*)d_in[1];
  const float* w1     = (const float*)d_in[2];
  const float* w2     = (const float*)d_in[3];
  const float* b2     = (const float*)d_in[4];
  const float* weight = (const float*)d_in[5];
  const float* bias   = (const float*)d_in[6];
  float* out = (float*)d_out;
  char* ws = (char*)d_ws;

  const size_t WAGG_BYTES = (size_t)32 * 256 * 768 * 2;    // 12,582,912
  bf16* Wagg  = (bf16*)ws;
  float* attn = (float*)(ws + WAGG_BYTES);
  float* aggb = (float*)(ws + WAGG_BYTES + 512);

  attn_kernel<<<32, 256, 0, stream>>>(ref, w1, w2, b2, bias, attn, aggb);
  aggw_kernel<<<dim3(256, 32), 256, 0, stream>>>(weight, attn, Wagg);
  conv_kernel<<<512, 256, 0, stream>>>(x, Wagg, aggb, out);
}